// Round 1
// 210.625 us; speedup vs baseline: 1.1189x; 1.1189x over previous
//
#include <hip/hip_runtime.h>
#include <hip/hip_bf16.h>

typedef __attribute__((ext_vector_type(8))) short bf16x8;
typedef __attribute__((ext_vector_type(4))) float f32x4;

#define SEQ 2048
#define DM  512
#define NH  8
#define DH  64
// (1/sqrt(2048)) * log2(e): folded into Q so scores come out ready for exp2
#define QSCALE 0.031879360f

__device__ __forceinline__ unsigned short f2bf(float f) {
  unsigned int u = __float_as_uint(f);
  unsigned int r = 0x7FFFu + ((u >> 16) & 1u);
  return (unsigned short)((u + r) >> 16);
}

// load 8 contiguous f32, convert to bf16
__device__ __forceinline__ void load8f(const float* __restrict__ s,
                                       unsigned short* __restrict__ o) {
  float4 v0 = *(const float4*)s;
  float4 v1 = *(const float4*)(s + 4);
  o[0] = f2bf(v0.x); o[1] = f2bf(v0.y); o[2] = f2bf(v0.z); o[3] = f2bf(v0.w);
  o[4] = f2bf(v1.x); o[5] = f2bf(v1.y); o[6] = f2bf(v1.z); o[7] = f2bf(v1.w);
}

// ---------- fused weight prep: Wq/Wk/Wv per-head transpose + Wo transpose (f32->bf16) ----------
// 256 blocks: [0,64) Wq, [64,128) Wk, [128,192) Wv, [192,256) Wo
__global__ __launch_bounds__(256) void weight_prep(const float* __restrict__ Wq,
                                                   const float* __restrict__ Wk,
                                                   const float* __restrict__ Wv,
                                                   const float* __restrict__ Wo,
                                                   unsigned short* __restrict__ Wqt,
                                                   unsigned short* __restrict__ Wkt,
                                                   unsigned short* __restrict__ Wvt,
                                                   unsigned short* __restrict__ Wot) {
  const int which = blockIdx.x >> 6, wi = blockIdx.x & 63;
  const float* src;
  unsigned short* dst;
  int R, C, r0, c0;
  if (which < 3) {
    const float* W = (which == 0) ? Wq : (which == 1) ? Wk : Wv;
    unsigned short* D = (which == 0) ? Wqt : (which == 1) ? Wkt : Wvt;
    int h = wi >> 3;
    src = W + (size_t)h * 512 * 64;
    dst = D + (size_t)h * 64 * 512;
    R = 512; C = 64; r0 = (wi & 7) * 64; c0 = 0;
  } else {
    src = Wo; dst = Wot;
    R = 512; C = 512; r0 = (wi >> 3) * 64; c0 = (wi & 7) * 64;
  }
  __shared__ __align__(16) unsigned short T[64][72];
  const int tid = threadIdx.x;
#pragma unroll
  for (int i = 0; i < 2; ++i) {
    int c = tid + 256 * i;
    int lr = c >> 3, lc = (c & 7) * 8;
    __align__(16) unsigned short tmp[8];
    load8f(src + (size_t)(r0 + lr) * C + c0 + lc, tmp);
    *(uint4*)&T[lr][lc] = *(const uint4*)tmp;
  }
  __syncthreads();
#pragma unroll
  for (int i = 0; i < 2; ++i) {
    int c = tid + 256 * i;
    int orow = c >> 3, och = (c & 7) * 8;
    __align__(16) unsigned short tmp[8];
#pragma unroll
    for (int j = 0; j < 8; ++j) tmp[j] = T[och + j][orow];
    *(uint4*)(dst + (size_t)(c0 + orow) * R + r0 + och) = *(uint4*)tmp;
  }
}

// ---------- fused QKV projection, 128x128 tiles ----------
// z=0: Q (pre-scaled by QSCALE) -> Qp [B,H,S,64]; z=1: K -> Kp; z=2: V -> Vpt [B,H,64,S]
__global__ __launch_bounds__(256, 4) void proj128(const float* __restrict__ q,
                                                  const float* __restrict__ k,
                                                  const float* __restrict__ v,
                                                  const unsigned short* __restrict__ Wqt,
                                                  const unsigned short* __restrict__ Wkt,
                                                  const unsigned short* __restrict__ Wvt,
                                                  const float* __restrict__ bq,
                                                  const float* __restrict__ bk,
                                                  const float* __restrict__ bv,
                                                  unsigned short* __restrict__ Qp,
                                                  unsigned short* __restrict__ Kp,
                                                  unsigned short* __restrict__ Vpt) {
  const int which = blockIdx.z;
  const float* X = (which == 0) ? q : (which == 1) ? k : v;
  const unsigned short* Wt = (which == 0) ? Wqt : (which == 1) ? Wkt : Wvt;  // [512n][512k]
  const float* bias = (which == 0) ? bq : (which == 1) ? bk : bv;
  unsigned short* out = (which == 0) ? Qp : (which == 1) ? Kp : Vpt;
  const float ps = (which == 0) ? QSCALE : 1.0f;

  const int m0 = blockIdx.x * 128;
  const int n0 = blockIdx.y * 128;
  __shared__ __align__(16) unsigned short smem[2][128][72];
  unsigned short (*As)[72] = smem[0];
  unsigned short (*Bs)[72] = smem[1];
  const int tid  = threadIdx.x;
  const int wave = tid >> 6, lane = tid & 63;
  const int l15  = lane & 15, quad = lane >> 4;
  const int rb = (wave >> 1) * 64, cb = (wave & 1) * 64;

  f32x4 acc[4][4];
#pragma unroll
  for (int i = 0; i < 4; ++i)
#pragma unroll
    for (int f = 0; f < 4; ++f) acc[i][f] = (f32x4){0.f, 0.f, 0.f, 0.f};

  for (int k0 = 0; k0 < DM; k0 += 64) {
    __syncthreads();
#pragma unroll
    for (int i = 0; i < 4; ++i) {
      int c = tid + 256 * i;             // 1024 slots x 8 elems = 128x64
      int lr = c >> 3, lc = (c & 7) * 8;
      __align__(16) unsigned short tmp[8];
      load8f(X + (size_t)(m0 + lr) * DM + k0 + lc, tmp);
      *(uint4*)&As[lr][lc] = *(const uint4*)tmp;
      *(uint4*)&Bs[lr][lc] = *(const uint4*)(Wt + (size_t)(n0 + lr) * DM + k0 + lc);
    }
    __syncthreads();
#pragma unroll
    for (int kc = 0; kc < 2; ++kc) {
      bf16x8 av[4], bv4[4];
#pragma unroll
      for (int i = 0; i < 4; ++i) av[i]  = *(const bf16x8*)&As[rb + 16 * i + l15][kc * 32 + quad * 8];
#pragma unroll
      for (int f = 0; f < 4; ++f) bv4[f] = *(const bf16x8*)&Bs[cb + 16 * f + l15][kc * 32 + quad * 8];
#pragma unroll
      for (int i = 0; i < 4; ++i)
#pragma unroll
        for (int f = 0; f < 4; ++f)
          acc[i][f] = __builtin_amdgcn_mfma_f32_16x16x32_bf16(av[i], bv4[f], acc[i][f], 0, 0, 0);
    }
  }

  if (which < 2) {  // Q/K: [B,H,S,64]
#pragma unroll
    for (int i = 0; i < 4; ++i)
#pragma unroll
      for (int f = 0; f < 4; ++f)
#pragma unroll
        for (int r = 0; r < 4; ++r) {
          int m = m0 + rb + 16 * i + quad * 4 + r;
          int col = n0 + cb + 16 * f + l15;
          int head = col >> 6, o = col & 63;
          int b = m >> 11, s = m & (SEQ - 1);
          float val = (acc[i][f][r] + bias[col]) * ps;
          out[(((size_t)(b * NH + head) * SEQ + s) << 6) + o] = f2bf(val);
        }
  } else {  // V: emit V^T [B,H,64,S] via per-wave LDS bounce transpose
    __syncthreads();  // all waves done reading As/Bs
    unsigned short* T = &smem[0][0][0] + wave * 4608;  // [64][72] per wave
#pragma unroll
    for (int i = 0; i < 4; ++i)
#pragma unroll
      for (int f = 0; f < 4; ++f)
#pragma unroll
        for (int r = 0; r < 4; ++r) {
          int lrow = 16 * i + quad * 4 + r;   // seq-local
          int lcol = 16 * f + l15;            // dh-local
          int col = n0 + cb + 16 * f + l15;
          T[lcol * 72 + lrow] = f2bf(acc[i][f][r] + bias[col]);
        }
    const int mbase = m0 + rb;
    const int b = mbase >> 11, sbase = mbase & (SEQ - 1);
    const int head = (n0 + cb) >> 6;
    unsigned short* dstb = out + ((size_t)(b * NH + head) * DH) * SEQ + sbase;
#pragma unroll
    for (int j = 0; j < 8; ++j) {
      int dh = (lane >> 3) + j * 8;
      int sc = (lane & 7) * 8;
      *(uint4*)(dstb + (size_t)dh * SEQ + sc) = *(const uint4*)&T[dh * 72 + sc];
    }
  }
}

// ---------- flash attention (no-max exp2 softmax) -> concat bf16 [B,SEQ,DM] ----------
// Qp pre-scaled by QSCALE.
// Causal-pairing: block (ip, bh) handles q-tiles qa=ip and qb=31-ip: (qa+1)+(qb+1)=33
// tile-units for EVERY block -> perfect work balance (old grid put 4 same-qt blocks on
// each CU: 4..128 units/CU vs 66 balanced). K/V tile staged once serves both q-tiles.
// Single barrier/iter, double-buffered LDS, global->reg loads issued 2 tiles ahead (T14).
__global__ __launch_bounds__(256, 2) void attn_kernel(const unsigned short* __restrict__ Qp,
                                                      const unsigned short* __restrict__ Kp,
                                                      const unsigned short* __restrict__ Vpt,
                                                      unsigned short* __restrict__ concat) {
  const int ip = blockIdx.x;            // pair index 0..15
  const int bh = blockIdx.y;
  const int b = bh >> 3, h = bh & 7;
  const int qa = ip, qb = 31 - ip;      // qa < qb always
  __shared__ __align__(16) unsigned short Ks[2][64][72], Vts[2][64][72], Ps[2][64][72];
  const int tid  = threadIdx.x;
  const int wave = tid >> 6, lane = tid & 63;
  const int l15  = lane & 15, quad = lane >> 4;
  const unsigned short* Qb = Qp  + (size_t)bh * SEQ * DH;
  const unsigned short* Kb = Kp  + (size_t)bh * SEQ * DH;
  const unsigned short* Vb = Vpt + (size_t)bh * DH * SEQ;

  // Q fragments for both tiles straight to registers
  bf16x8 aqa[2], aqb[2];
#pragma unroll
  for (int kc = 0; kc < 2; ++kc) {
    aqa[kc] = *(const bf16x8*)(Qb + (size_t)(qa * 64 + 16 * wave + l15) * DH + kc * 32 + quad * 8);
    aqb[kc] = *(const bf16x8*)(Qb + (size_t)(qb * 64 + 16 * wave + l15) * DH + kc * 32 + quad * 8);
  }

  float la[4], lb[4];
  f32x4 Oa[4], Ob[4];
#pragma unroll
  for (int r = 0; r < 4; ++r) { la[r] = 0.f; lb[r] = 0.f; }
#pragma unroll
  for (int f = 0; f < 4; ++f) { Oa[f] = (f32x4){0.f, 0.f, 0.f, 0.f}; Ob[f] = (f32x4){0.f, 0.f, 0.f, 0.f}; }

  // staging registers: K tile = 64x64 bf16 = 512 uint4 chunks; thread owns chunks tid, tid+256
  const int sr = tid >> 3, sc = (tid & 7) * 8;   // (tid+256)>>3 = sr+32, same sc
  uint4 kst0, kst1, vst0, vst1;

#define STAGE_LOAD(lt_) do {                                                   \
    kst0 = *(const uint4*)(Kb + (size_t)((lt_) * 64 + sr) * DH + sc);          \
    kst1 = *(const uint4*)(Kb + (size_t)((lt_) * 64 + sr + 32) * DH + sc);     \
    vst0 = *(const uint4*)(Vb + (size_t)sr * SEQ + (lt_) * 64 + sc);           \
    vst1 = *(const uint4*)(Vb + (size_t)(sr + 32) * SEQ + (lt_) * 64 + sc);    \
  } while (0)

#define STAGE_WRITE(bi_) do {                                                  \
    *(uint4*)&Ks[bi_][sr][sc]        = kst0;                                   \
    *(uint4*)&Ks[bi_][sr + 32][sc]   = kst1;                                   \
    *(uint4*)&Vts[bi_][sr][sc]       = vst0;                                   \
    *(uint4*)&Vts[bi_][sr + 32][sc]  = vst1;                                   \
  } while (0)

  // prologue: tile 0 -> buf 0; tile 1 -> regs (qb >= 16, so tiles 0 and 1 always exist)
  STAGE_LOAD(0);
  STAGE_WRITE(0);
  STAGE_LOAD(1);
  __syncthreads();

#pragma unroll 1
  for (int lt = 0; lt <= qb; ++lt) {
    const int cur = lt & 1;
    // write staged regs (tile lt+1) into the other buffer; prev iter's barrier
    // guarantees its readers (iter lt-1) are done
    if (lt < qb) STAGE_WRITE(cur ^ 1);
    // issue global loads for tile lt+2 -> latency hides under this iter's compute
    if (lt + 2 <= qb) STAGE_LOAD(lt + 2);

    const bool act_a = (lt <= qa);
    const int l0 = lt * 64;

    // S' = (Q*QSCALE) K^T  (already includes log2e); K frags shared by both q-tiles
    f32x4 Sa[4], Sb[4];
#pragma unroll
    for (int f = 0; f < 4; ++f) { Sa[f] = (f32x4){0.f, 0.f, 0.f, 0.f}; Sb[f] = (f32x4){0.f, 0.f, 0.f, 0.f}; }
#pragma unroll
    for (int kc = 0; kc < 2; ++kc) {
      bf16x8 bk[4];
#pragma unroll
      for (int f = 0; f < 4; ++f) bk[f] = *(const bf16x8*)&Ks[cur][16 * f + l15][kc * 32 + quad * 8];
#pragma unroll
      for (int f = 0; f < 4; ++f) Sb[f] = __builtin_amdgcn_mfma_f32_16x16x32_bf16(aqb[kc], bk[f], Sb[f], 0, 0, 0);
      if (act_a) {
#pragma unroll
        for (int f = 0; f < 4; ++f) Sa[f] = __builtin_amdgcn_mfma_f32_16x16x32_bf16(aqa[kc], bk[f], Sa[f], 0, 0, 0);
      }
    }
    if (lt == qb) {
      const int mrow = qb * 64 + 16 * wave + quad * 4;
#pragma unroll
      for (int f = 0; f < 4; ++f)
#pragma unroll
        for (int r = 0; r < 4; ++r)
          if (l0 + 16 * f + l15 > mrow + r) Sb[f][r] = -1e30f;
    }
    if (lt == qa) {
      const int mrow = qa * 64 + 16 * wave + quad * 4;
#pragma unroll
      for (int f = 0; f < 4; ++f)
#pragma unroll
        for (int r = 0; r < 4; ++r)
          if (l0 + 16 * f + l15 > mrow + r) Sa[f][r] = -1e30f;
    }
    // p = exp2(S'), accumulate per-lane row partial sums (reduced once at end)
#pragma unroll
    for (int f = 0; f < 4; ++f)
#pragma unroll
      for (int r = 0; r < 4; ++r) {
        float p = __builtin_amdgcn_exp2f(Sb[f][r]);
        lb[r] += p;
        Ps[0][16 * wave + quad * 4 + r][16 * f + l15] = f2bf(p);  // wave-private rows
      }
    if (act_a) {
#pragma unroll
      for (int f = 0; f < 4; ++f)
#pragma unroll
        for (int r = 0; r < 4; ++r) {
          float p = __builtin_amdgcn_exp2f(Sa[f][r]);
          la[r] += p;
          Ps[1][16 * wave + quad * 4 + r][16 * f + l15] = f2bf(p);
        }
    }
    // O += P @ V ; V frags shared by both q-tiles
#pragma unroll
    for (int kc = 0; kc < 2; ++kc) {
      bf16x8 bvv[4];
#pragma unroll
      for (int f = 0; f < 4; ++f) bvv[f] = *(const bf16x8*)&Vts[cur][16 * f + l15][kc * 32 + quad * 8];
      bf16x8 apb = *(const bf16x8*)&Ps[0][16 * wave + l15][kc * 32 + quad * 8];
#pragma unroll
      for (int f = 0; f < 4; ++f) Ob[f] = __builtin_amdgcn_mfma_f32_16x16x32_bf16(apb, bvv[f], Ob[f], 0, 0, 0);
      if (act_a) {
        bf16x8 apa = *(const bf16x8*)&Ps[1][16 * wave + l15][kc * 32 + quad * 8];
#pragma unroll
        for (int f = 0; f < 4; ++f) Oa[f] = __builtin_amdgcn_mfma_f32_16x16x32_bf16(apa, bvv[f], Oa[f], 0, 0, 0);
      }
    }
    __syncthreads();
  }
#undef STAGE_LOAD
#undef STAGE_WRITE

  // single row-sum reduction across the 16 lanes sharing each row
#pragma unroll
  for (int d = 1; d < 16; d <<= 1)
#pragma unroll
    for (int r = 0; r < 4; ++r) {
      lb[r] += __shfl_xor(lb[r], d);
      la[r] += __shfl_xor(la[r], d);
    }

#pragma unroll
  for (int f = 0; f < 4; ++f)
#pragma unroll
    for (int r = 0; r < 4; ++r) {
      const int col = h * DH + 16 * f + l15;
      const int rowb = qb * 64 + 16 * wave + quad * 4 + r;
      concat[(size_t)(b * SEQ + rowb) * DM + col] = f2bf(Ob[f][r] / lb[r]);
      const int rowa = qa * 64 + 16 * wave + quad * 4 + r;
      concat[(size_t)(b * SEQ + rowa) * DM + col] = f2bf(Oa[f][r] / la[r]);
    }
}

// ---------- output projection: out_f32 = concat_bf16 @ Wot^T + b_o ----------
__global__ __launch_bounds__(256) void gemm_out(const unsigned short* __restrict__ A,
                                                const unsigned short* __restrict__ Bt,
                                                const float* __restrict__ bias,
                                                float* __restrict__ out) {
  const int m0 = blockIdx.x * 64;
  const int nbase = blockIdx.y * 256;
  __shared__ __align__(16) unsigned short Bs[64][72];
  const int tid  = threadIdx.x;
  const int wave = tid >> 6, lane = tid & 63;
  const int l15  = lane & 15, quad = lane >> 4;

  bf16x8 afr[16];  // per-wave A rows held in registers across all n0 tiles
  const unsigned short* arow = A + (size_t)(m0 + 16 * wave + l15) * DM;
#pragma unroll
  for (int k0i = 0; k0i < 8; ++k0i)
#pragma unroll
    for (int kc = 0; kc < 2; ++kc)
      afr[k0i * 2 + kc] = *(const bf16x8*)(arow + k0i * 64 + kc * 32 + quad * 8);

  for (int n0 = nbase; n0 < nbase + 256; n0 += 64) {
    f32x4 acc[4];
#pragma unroll
    for (int f = 0; f < 4; ++f) acc[f] = (f32x4){0.f, 0.f, 0.f, 0.f};
    for (int k0i = 0; k0i < 8; ++k0i) {
      __syncthreads();
#pragma unroll
      for (int i = 0; i < 2; ++i) {
        int c = tid + 256 * i;
        int lr = c >> 3, lc = (c & 7) * 8;
        *(uint4*)&Bs[lr][lc] = *(const uint4*)(Bt + (size_t)(n0 + lr) * DM + k0i * 64 + lc);
      }
      __syncthreads();
#pragma unroll
      for (int kc = 0; kc < 2; ++kc)
#pragma unroll
        for (int f = 0; f < 4; ++f) {
          bf16x8 bfv = *(const bf16x8*)&Bs[16 * f + l15][kc * 32 + quad * 8];
          acc[f] = __builtin_amdgcn_mfma_f32_16x16x32_bf16(afr[k0i * 2 + kc], bfv, acc[f], 0, 0, 0);
        }
    }
#pragma unroll
    for (int f = 0; f < 4; ++f)
#pragma unroll
      for (int r = 0; r < 4; ++r) {
        int row = 16 * wave + quad * 4 + r;
        int col = 16 * f + l15;
        out[(size_t)(m0 + row) * DM + n0 + col] = acc[f][r] + bias[n0 + col];
      }
  }
}

extern "C" void kernel_launch(void* const* d_in, const int* in_sizes, int n_in,
                              void* d_out, int out_size, void* d_ws, size_t ws_size,
                              hipStream_t stream) {
  const float* query = (const float*)d_in[0];
  const float* key   = (const float*)d_in[1];
  const float* value = (const float*)d_in[2];
  const float* W_q   = (const float*)d_in[3];
  const float* b_q   = (const float*)d_in[4];
  const float* W_k   = (const float*)d_in[5];
  const float* b_k   = (const float*)d_in[6];
  const float* W_v   = (const float*)d_in[7];
  const float* b_v   = (const float*)d_in[8];
  const float* W_o   = (const float*)d_in[9];
  const float* b_o   = (const float*)d_in[10];
  float* out = (float*)d_out;

  char* ws = (char*)d_ws;
  unsigned short* Wqt    = (unsigned short*)(ws + 0);         // [H][64][512] bf16
  unsigned short* Wkt    = (unsigned short*)(ws + 524288);
  unsigned short* Wvt    = (unsigned short*)(ws + 1048576);
  unsigned short* Wot    = (unsigned short*)(ws + 1572864);   // [512][512] bf16
  unsigned short* Qp     = (unsigned short*)(ws + 2097152);   // [B,H,S,64] bf16 8 MB
  unsigned short* Kp     = (unsigned short*)(ws + 10485760);
  unsigned short* Vpt    = (unsigned short*)(ws + 18874368);  // [B,H,64,S] bf16 8 MB
  unsigned short* concat = (unsigned short*)(ws + 27262976);  // [B,S,512] bf16 8 MB

  weight_prep<<<dim3(256), 256, 0, stream>>>(W_q, W_k, W_v, W_o, Wqt, Wkt, Wvt, Wot);

  proj128<<<dim3(64, 4, 3), 256, 0, stream>>>(query, key, value, Wqt, Wkt, Wvt,
                                              b_q, b_k, b_v, Qp, Kp, Vpt);

  attn_kernel<<<dim3(16, 32), 256, 0, stream>>>(Qp, Kp, Vpt, concat);

  gemm_out<<<dim3(128, 2), 256, 0, stream>>>(concat, Wot, b_o, out);
}

// Round 2
// 205.231 us; speedup vs baseline: 1.1483x; 1.0263x over previous
//
#include <hip/hip_runtime.h>
#include <hip/hip_bf16.h>

typedef __attribute__((ext_vector_type(8))) short bf16x8;
typedef __attribute__((ext_vector_type(4))) float f32x4;

#define SEQ 2048
#define DM  512
#define NH  8
#define DH  64
// (1/sqrt(2048)) * log2(e): folded into Q so scores come out ready for exp2
#define QSCALE 0.031879360f

__device__ __forceinline__ unsigned short f2bf(float f) {
  unsigned int u = __float_as_uint(f);
  unsigned int r = 0x7FFFu + ((u >> 16) & 1u);
  return (unsigned short)((u + r) >> 16);
}

// load 8 contiguous f32, convert to bf16
__device__ __forceinline__ void load8f(const float* __restrict__ s,
                                       unsigned short* __restrict__ o) {
  float4 v0 = *(const float4*)s;
  float4 v1 = *(const float4*)(s + 4);
  o[0] = f2bf(v0.x); o[1] = f2bf(v0.y); o[2] = f2bf(v0.z); o[3] = f2bf(v0.w);
  o[4] = f2bf(v1.x); o[5] = f2bf(v1.y); o[6] = f2bf(v1.z); o[7] = f2bf(v1.w);
}

// ---------- fused weight prep: Wq/Wk/Wv per-head transpose + Wo transpose (f32->bf16) ----------
// 256 blocks: [0,64) Wq, [64,128) Wk, [128,192) Wv, [192,256) Wo
__global__ __launch_bounds__(256) void weight_prep(const float* __restrict__ Wq,
                                                   const float* __restrict__ Wk,
                                                   const float* __restrict__ Wv,
                                                   const float* __restrict__ Wo,
                                                   unsigned short* __restrict__ Wqt,
                                                   unsigned short* __restrict__ Wkt,
                                                   unsigned short* __restrict__ Wvt,
                                                   unsigned short* __restrict__ Wot) {
  const int which = blockIdx.x >> 6, wi = blockIdx.x & 63;
  const float* src;
  unsigned short* dst;
  int R, C, r0, c0;
  if (which < 3) {
    const float* W = (which == 0) ? Wq : (which == 1) ? Wk : Wv;
    unsigned short* D = (which == 0) ? Wqt : (which == 1) ? Wkt : Wvt;
    int h = wi >> 3;
    src = W + (size_t)h * 512 * 64;
    dst = D + (size_t)h * 64 * 512;
    R = 512; C = 64; r0 = (wi & 7) * 64; c0 = 0;
  } else {
    src = Wo; dst = Wot;
    R = 512; C = 512; r0 = (wi >> 3) * 64; c0 = (wi & 7) * 64;
  }
  __shared__ __align__(16) unsigned short T[64][72];
  const int tid = threadIdx.x;
#pragma unroll
  for (int i = 0; i < 2; ++i) {
    int c = tid + 256 * i;
    int lr = c >> 3, lc = (c & 7) * 8;
    __align__(16) unsigned short tmp[8];
    load8f(src + (size_t)(r0 + lr) * C + c0 + lc, tmp);
    *(uint4*)&T[lr][lc] = *(const uint4*)tmp;
  }
  __syncthreads();
#pragma unroll
  for (int i = 0; i < 2; ++i) {
    int c = tid + 256 * i;
    int orow = c >> 3, och = (c & 7) * 8;
    __align__(16) unsigned short tmp[8];
#pragma unroll
    for (int j = 0; j < 8; ++j) tmp[j] = T[och + j][orow];
    *(uint4*)(dst + (size_t)(c0 + orow) * R + r0 + och) = *(uint4*)tmp;
  }
}

// ---------- fused QKV projection, 128x128 tiles ----------
// z=0: Q (pre-scaled by QSCALE) -> Qp [B,H,S,64]; z=1: K -> Kp; z=2: V -> Vpt [B,H,64,S]
__global__ __launch_bounds__(256, 4) void proj128(const float* __restrict__ q,
                                                  const float* __restrict__ k,
                                                  const float* __restrict__ v,
                                                  const unsigned short* __restrict__ Wqt,
                                                  const unsigned short* __restrict__ Wkt,
                                                  const unsigned short* __restrict__ Wvt,
                                                  const float* __restrict__ bq,
                                                  const float* __restrict__ bk,
                                                  const float* __restrict__ bv,
                                                  unsigned short* __restrict__ Qp,
                                                  unsigned short* __restrict__ Kp,
                                                  unsigned short* __restrict__ Vpt) {
  const int which = blockIdx.z;
  const float* X = (which == 0) ? q : (which == 1) ? k : v;
  const unsigned short* Wt = (which == 0) ? Wqt : (which == 1) ? Wkt : Wvt;  // [512n][512k]
  const float* bias = (which == 0) ? bq : (which == 1) ? bk : bv;
  unsigned short* out = (which == 0) ? Qp : (which == 1) ? Kp : Vpt;
  const float ps = (which == 0) ? QSCALE : 1.0f;

  const int m0 = blockIdx.x * 128;
  const int n0 = blockIdx.y * 128;
  __shared__ __align__(16) unsigned short smem[2][128][72];
  unsigned short (*As)[72] = smem[0];
  unsigned short (*Bs)[72] = smem[1];
  const int tid  = threadIdx.x;
  const int wave = tid >> 6, lane = tid & 63;
  const int l15  = lane & 15, quad = lane >> 4;
  const int rb = (wave >> 1) * 64, cb = (wave & 1) * 64;

  f32x4 acc[4][4];
#pragma unroll
  for (int i = 0; i < 4; ++i)
#pragma unroll
    for (int f = 0; f < 4; ++f) acc[i][f] = (f32x4){0.f, 0.f, 0.f, 0.f};

  for (int k0 = 0; k0 < DM; k0 += 64) {
    __syncthreads();
#pragma unroll
    for (int i = 0; i < 4; ++i) {
      int c = tid + 256 * i;             // 1024 slots x 8 elems = 128x64
      int lr = c >> 3, lc = (c & 7) * 8;
      __align__(16) unsigned short tmp[8];
      load8f(X + (size_t)(m0 + lr) * DM + k0 + lc, tmp);
      *(uint4*)&As[lr][lc] = *(const uint4*)tmp;
      *(uint4*)&Bs[lr][lc] = *(const uint4*)(Wt + (size_t)(n0 + lr) * DM + k0 + lc);
    }
    __syncthreads();
#pragma unroll
    for (int kc = 0; kc < 2; ++kc) {
      bf16x8 av[4], bv4[4];
#pragma unroll
      for (int i = 0; i < 4; ++i) av[i]  = *(const bf16x8*)&As[rb + 16 * i + l15][kc * 32 + quad * 8];
#pragma unroll
      for (int f = 0; f < 4; ++f) bv4[f] = *(const bf16x8*)&Bs[cb + 16 * f + l15][kc * 32 + quad * 8];
#pragma unroll
      for (int i = 0; i < 4; ++i)
#pragma unroll
        for (int f = 0; f < 4; ++f)
          acc[i][f] = __builtin_amdgcn_mfma_f32_16x16x32_bf16(av[i], bv4[f], acc[i][f], 0, 0, 0);
    }
  }

  if (which < 2) {  // Q/K: [B,H,S,64]
#pragma unroll
    for (int i = 0; i < 4; ++i)
#pragma unroll
      for (int f = 0; f < 4; ++f)
#pragma unroll
        for (int r = 0; r < 4; ++r) {
          int m = m0 + rb + 16 * i + quad * 4 + r;
          int col = n0 + cb + 16 * f + l15;
          int head = col >> 6, o = col & 63;
          int b = m >> 11, s = m & (SEQ - 1);
          float val = (acc[i][f][r] + bias[col]) * ps;
          out[(((size_t)(b * NH + head) * SEQ + s) << 6) + o] = f2bf(val);
        }
  } else {  // V: emit V^T [B,H,64,S] via per-wave LDS bounce transpose
    __syncthreads();  // all waves done reading As/Bs
    unsigned short* T = &smem[0][0][0] + wave * 4608;  // [64][72] per wave
#pragma unroll
    for (int i = 0; i < 4; ++i)
#pragma unroll
      for (int f = 0; f < 4; ++f)
#pragma unroll
        for (int r = 0; r < 4; ++r) {
          int lrow = 16 * i + quad * 4 + r;   // seq-local
          int lcol = 16 * f + l15;            // dh-local
          int col = n0 + cb + 16 * f + l15;
          T[lcol * 72 + lrow] = f2bf(acc[i][f][r] + bias[col]);
        }
    const int mbase = m0 + rb;
    const int b = mbase >> 11, sbase = mbase & (SEQ - 1);
    const int head = (n0 + cb) >> 6;
    unsigned short* dstb = out + ((size_t)(b * NH + head) * DH) * SEQ + sbase;
#pragma unroll
    for (int j = 0; j < 8; ++j) {
      int dh = (lane >> 3) + j * 8;
      int sc = (lane & 7) * 8;
      *(uint4*)(dstb + (size_t)dh * SEQ + sc) = *(const uint4*)&T[dh * 72 + sc];
    }
  }
}

// ---------- flash attention (no-max exp2 softmax) -> concat bf16 [B,SEQ,DM] ----------
// Qp pre-scaled by QSCALE.
// Causal-pairing: block (bh, ip) handles q-tiles qa=ip and qb=31-ip (33 tile-units per
// block, perfectly balanced). 512 threads / 8 waves: waves 0-3 own qb's four 16-row
// quarters, waves 4-7 own qa's. One tile-chain per wave per iter (was two serially) and
// 16 waves/CU (4/SIMD) to hide the QK->exp2->LDS->PV latency chain (was 2/SIMD).
// K/V tile staged once per block serves all 8 waves. grid x=bh so all blocks of one bh
// land on one XCD (id%8 = bh%8) -> K/V stream stays L2-resident.
__global__ __launch_bounds__(512, 4) void attn_kernel(const unsigned short* __restrict__ Qp,
                                                      const unsigned short* __restrict__ Kp,
                                                      const unsigned short* __restrict__ Vpt,
                                                      unsigned short* __restrict__ concat) {
  const int bh = blockIdx.x;            // 32
  const int ip = blockIdx.y;            // pair index 0..15
  const int b = bh >> 3, h = bh & 7;
  const int qa = ip, qb = 31 - ip;      // qa < qb always
  __shared__ __align__(16) unsigned short Ks[2][64][72], Vts[2][64][72], Ps[128][72];
  const int tid  = threadIdx.x;
  const int wave = tid >> 6, lane = tid & 63;
  const int l15  = lane & 15, quad = lane >> 4;
  const int w4   = wave & 3;
  const bool isB = wave < 4;            // waves 0-3 -> qb, waves 4-7 -> qa
  const int qt   = isB ? qb : qa;
  const unsigned short* Qb = Qp  + (size_t)bh * SEQ * DH;
  const unsigned short* Kb = Kp  + (size_t)bh * SEQ * DH;
  const unsigned short* Vb = Vpt + (size_t)bh * DH * SEQ;

  // own q-tile fragments straight to registers (16 rows per wave)
  bf16x8 aq[2];
#pragma unroll
  for (int kc = 0; kc < 2; ++kc)
    aq[kc] = *(const bf16x8*)(Qb + (size_t)(qt * 64 + 16 * w4 + l15) * DH + kc * 32 + quad * 8);

  float l_lane[4];
  f32x4 Of[4];
#pragma unroll
  for (int r = 0; r < 4; ++r) l_lane[r] = 0.f;
#pragma unroll
  for (int f = 0; f < 4; ++f) Of[f] = (f32x4){0.f, 0.f, 0.f, 0.f};

  // staging: K tile 64x64 bf16 = 512 uint4 chunks; 512 threads own 1 chunk each (K and V)
  const int sr = tid >> 3, sc = (tid & 7) * 8;
  uint4 kst, vst;

#define STAGE_LOAD(lt_) do {                                                   \
    kst = *(const uint4*)(Kb + (size_t)((lt_) * 64 + sr) * DH + sc);           \
    vst = *(const uint4*)(Vb + (size_t)sr * SEQ + (lt_) * 64 + sc);            \
  } while (0)

#define STAGE_WRITE(bi_) do {                                                  \
    *(uint4*)&Ks[bi_][sr][sc]  = kst;                                          \
    *(uint4*)&Vts[bi_][sr][sc] = vst;                                          \
  } while (0)

  // prologue: tile 0 -> buf 0; tile 1 -> regs (qb >= 16 so tiles 0,1 always exist)
  STAGE_LOAD(0);
  STAGE_WRITE(0);
  STAGE_LOAD(1);
  __syncthreads();

#pragma unroll 1
  for (int lt = 0; lt <= qb; ++lt) {
    const int cur = lt & 1;
    // write staged regs (tile lt+1) into other buffer; prev iter's end barrier
    // guarantees its readers are done
    if (lt < qb) STAGE_WRITE(cur ^ 1);
    // issue global loads for tile lt+2 -> latency hides under this iter's compute
    if (lt + 2 <= qb) STAGE_LOAD(lt + 2);

    const bool act = isB || (lt <= qa);
    if (act) {
      const int l0 = lt * 64;
      // S' = (Q*QSCALE) K^T  (already includes log2e)
      f32x4 S[4];
#pragma unroll
      for (int f = 0; f < 4; ++f) S[f] = (f32x4){0.f, 0.f, 0.f, 0.f};
#pragma unroll
      for (int kc = 0; kc < 2; ++kc) {
#pragma unroll
        for (int f = 0; f < 4; ++f) {
          bf16x8 bk = *(const bf16x8*)&Ks[cur][16 * f + l15][kc * 32 + quad * 8];
          S[f] = __builtin_amdgcn_mfma_f32_16x16x32_bf16(aq[kc], bk, S[f], 0, 0, 0);
        }
      }
      if (lt == qt) {
        const int mrow = qt * 64 + 16 * w4 + quad * 4;
#pragma unroll
        for (int f = 0; f < 4; ++f)
#pragma unroll
          for (int r = 0; r < 4; ++r)
            if (l0 + 16 * f + l15 > mrow + r) S[f][r] = -1e30f;
      }
      // p = exp2(S'), accumulate per-lane row partial sums (reduced once at end)
#pragma unroll
      for (int f = 0; f < 4; ++f)
#pragma unroll
        for (int r = 0; r < 4; ++r) {
          float p = __builtin_amdgcn_exp2f(S[f][r]);
          l_lane[r] += p;
          Ps[wave * 16 + quad * 4 + r][16 * f + l15] = f2bf(p);  // wave-private rows
        }
      // O += P @ V
#pragma unroll
      for (int kc = 0; kc < 2; ++kc) {
        bf16x8 ap = *(const bf16x8*)&Ps[wave * 16 + l15][kc * 32 + quad * 8];
#pragma unroll
        for (int f = 0; f < 4; ++f) {
          bf16x8 bvv = *(const bf16x8*)&Vts[cur][16 * f + l15][kc * 32 + quad * 8];
          Of[f] = __builtin_amdgcn_mfma_f32_16x16x32_bf16(ap, bvv, Of[f], 0, 0, 0);
        }
      }
    }
    __syncthreads();
  }
#undef STAGE_LOAD
#undef STAGE_WRITE

  // row-sum reduction across the 16 lanes sharing each row
#pragma unroll
  for (int d = 1; d < 16; d <<= 1)
#pragma unroll
    for (int r = 0; r < 4; ++r) l_lane[r] += __shfl_xor(l_lane[r], d);

#pragma unroll
  for (int f = 0; f < 4; ++f)
#pragma unroll
    for (int r = 0; r < 4; ++r) {
      const int row = qt * 64 + 16 * w4 + quad * 4 + r;
      const int col = h * DH + 16 * f + l15;
      concat[(size_t)(b * SEQ + row) * DM + col] = f2bf(Of[f][r] / l_lane[r]);
    }
}

// ---------- output projection: out_f32 = concat_bf16 @ Wot^T + b_o ----------
__global__ __launch_bounds__(256) void gemm_out(const unsigned short* __restrict__ A,
                                                const unsigned short* __restrict__ Bt,
                                                const float* __restrict__ bias,
                                                float* __restrict__ out) {
  const int m0 = blockIdx.x * 64;
  const int nbase = blockIdx.y * 256;
  __shared__ __align__(16) unsigned short Bs[64][72];
  const int tid  = threadIdx.x;
  const int wave = tid >> 6, lane = tid & 63;
  const int l15  = lane & 15, quad = lane >> 4;

  bf16x8 afr[16];  // per-wave A rows held in registers across all n0 tiles
  const unsigned short* arow = A + (size_t)(m0 + 16 * wave + l15) * DM;
#pragma unroll
  for (int k0i = 0; k0i < 8; ++k0i)
#pragma unroll
    for (int kc = 0; kc < 2; ++kc)
      afr[k0i * 2 + kc] = *(const bf16x8*)(arow + k0i * 64 + kc * 32 + quad * 8);

  for (int n0 = nbase; n0 < nbase + 256; n0 += 64) {
    f32x4 acc[4];
#pragma unroll
    for (int f = 0; f < 4; ++f) acc[f] = (f32x4){0.f, 0.f, 0.f, 0.f};
    for (int k0i = 0; k0i < 8; ++k0i) {
      __syncthreads();
#pragma unroll
      for (int i = 0; i < 2; ++i) {
        int c = tid + 256 * i;
        int lr = c >> 3, lc = (c & 7) * 8;
        *(uint4*)&Bs[lr][lc] = *(const uint4*)(Bt + (size_t)(n0 + lr) * DM + k0i * 64 + lc);
      }
      __syncthreads();
#pragma unroll
      for (int kc = 0; kc < 2; ++kc)
#pragma unroll
        for (int f = 0; f < 4; ++f) {
          bf16x8 bfv = *(const bf16x8*)&Bs[16 * f + l15][kc * 32 + quad * 8];
          acc[f] = __builtin_amdgcn_mfma_f32_16x16x32_bf16(afr[k0i * 2 + kc], bfv, acc[f], 0, 0, 0);
        }
    }
#pragma unroll
    for (int f = 0; f < 4; ++f)
#pragma unroll
      for (int r = 0; r < 4; ++r) {
        int row = 16 * wave + quad * 4 + r;
        int col = 16 * f + l15;
        out[(size_t)(m0 + row) * DM + n0 + col] = acc[f][r] + bias[n0 + col];
      }
  }
}

extern "C" void kernel_launch(void* const* d_in, const int* in_sizes, int n_in,
                              void* d_out, int out_size, void* d_ws, size_t ws_size,
                              hipStream_t stream) {
  const float* query = (const float*)d_in[0];
  const float* key   = (const float*)d_in[1];
  const float* value = (const float*)d_in[2];
  const float* W_q   = (const float*)d_in[3];
  const float* b_q   = (const float*)d_in[4];
  const float* W_k   = (const float*)d_in[5];
  const float* b_k   = (const float*)d_in[6];
  const float* W_v   = (const float*)d_in[7];
  const float* b_v   = (const float*)d_in[8];
  const float* W_o   = (const float*)d_in[9];
  const float* b_o   = (const float*)d_in[10];
  float* out = (float*)d_out;

  char* ws = (char*)d_ws;
  unsigned short* Wqt    = (unsigned short*)(ws + 0);         // [H][64][512] bf16
  unsigned short* Wkt    = (unsigned short*)(ws + 524288);
  unsigned short* Wvt    = (unsigned short*)(ws + 1048576);
  unsigned short* Wot    = (unsigned short*)(ws + 1572864);   // [512][512] bf16
  unsigned short* Qp     = (unsigned short*)(ws + 2097152);   // [B,H,S,64] bf16 8 MB
  unsigned short* Kp     = (unsigned short*)(ws + 10485760);
  unsigned short* Vpt    = (unsigned short*)(ws + 18874368);  // [B,H,64,S] bf16 8 MB
  unsigned short* concat = (unsigned short*)(ws + 27262976);  // [B,S,512] bf16 8 MB

  weight_prep<<<dim3(256), 256, 0, stream>>>(W_q, W_k, W_v, W_o, Wqt, Wkt, Wvt, Wot);

  proj128<<<dim3(64, 4, 3), 256, 0, stream>>>(query, key, value, Wqt, Wkt, Wvt,
                                              b_q, b_k, b_v, Qp, Kp, Vpt);

  attn_kernel<<<dim3(32, 16), 512, 0, stream>>>(Qp, Kp, Vpt, concat);

  gemm_out<<<dim3(128, 2), 256, 0, stream>>>(concat, Wot, b_o, out);
}